// Round 3
// baseline (580.090 us; speedup 1.0000x reference)
//
#include <hip/hip_runtime.h>
#include <hip/hip_bf16.h>
#include <math.h>

typedef unsigned short u16;
typedef short bf16x8 __attribute__((ext_vector_type(8)));
typedef float f32x4  __attribute__((ext_vector_type(4)));
typedef float f32x16 __attribute__((ext_vector_type(16)));

#define IMG  256
#define NTOK 65536
#define NCH  128

// ---- ws layout (bytes); total ~32.3 MiB ----
#define OFF_VT   0ULL           // bf16 ungated v [b][c][n], 32 MiB
#define OFF_SQ   33554432ULL    // fp32 [b][128]
#define OFF_SK   33555456ULL    // fp32 [b][128]
#define OFF_WTE  33556480ULL    // bf16 WeffT [b][cout][c'] (64 KiB)
#define OFF_G    33622016ULL    // fp32 [bh][64][64] (64 KiB)
#define OFF_W3   33687552ULL    // bf16 W^T x3 [g][cout][cin] (96 KiB)
#define OFF_WP   33785856ULL    // bf16 Wp (32 KiB)
#define OFF_BP   33818624ULL    // bf16 bp
#define OFF_RES  33818880ULL    // bf16 rescale
#define OFF_C1   33819136ULL    // bf16 conv1 w
#define OFF_C2   33821696ULL    // bf16 conv2 w
#define OFF_FLAG 33824256ULL    // int: 1 = inputs are fp32

// ---- d_out scratch (dead after use; k_outc overwrites d_out fully) ----
#define GPARTF_EL 0ULL          // fp32 [512][2][64][64] = 4,194,304 floats (16.8 MB)
#define XC_U16    8388608ULL    // bf16 canonical X, 16,777,216 u16 (fp32 mode only)

static __device__ __forceinline__ float b2f(u16 u) {
    union { float f; unsigned int i; } x; x.i = ((unsigned int)u) << 16; return x.f;
}
static __device__ __forceinline__ u16 f2b(float f) {
    __hip_bfloat16 h = __float2bfloat16(f);
    return *reinterpret_cast<u16*>(&h);
}
static __device__ __forceinline__ u16 cvt_in(const void* p, int i, int fl) {
    return fl ? f2b(((const float*)p)[i]) : ((const u16*)p)[i];
}

// ---------------------------------------------------------------------------
// K-1: dtype probe. fp32 N(0,1) words have |x| in [1e-4,1e4]; bf16 pairs
// reinterpreted as fp32 have exponent ~2x bf16's -> never in that range.
// ---------------------------------------------------------------------------
__global__ void k_detect(const void* X, int* flag)
{
    __shared__ int cnt;
    if (threadIdx.x == 0) cnt = 0;
    __syncthreads();
    const float* xf = (const float*)X;
    int c = 0;
    #pragma unroll
    for (int i = 0; i < 4; ++i) {
        float v = fabsf(xf[threadIdx.x * 4 + i]);
        if (v > 1e-4f && v < 1e4f) c++;
    }
    atomicAdd(&cnt, c);
    __syncthreads();
    if (threadIdx.x == 0) flag[0] = (cnt > 512) ? 1 : 0;
}

// ---------------------------------------------------------------------------
// K0: canonicalize small weights into ws (bf16), incl. transposed W^T x3.
// ---------------------------------------------------------------------------
__global__ void k_prep(const void* Wq, const void* Wk, const void* Wv,
                       const void* Wp, const void* BP, const void* RES,
                       const void* C1, const void* C2,
                       u16* w3, u16* wp, u16* bp, u16* res, u16* c1, u16* c2,
                       const int* flag)
{
    const int fl = flag[0];
    int idx = blockIdx.x * 256 + threadIdx.x;
    if (idx < 49152) {
        int g = idx >> 14, r = idx & 16383;
        int cin = r >> 7, cout = r & 127;
        const void* s = (g == 0) ? Wq : (g == 1) ? Wk : Wv;
        w3[g * 16384 + cout * 128 + cin] = cvt_in(s, cin * 128 + cout, fl);
    } else if (idx < 65536) {
        int i = idx - 49152; wp[i] = cvt_in(Wp, i, fl);
    } else if (idx < 65664) {
        int i = idx - 65536; bp[i] = cvt_in(BP, i, fl);
    } else if (idx < 65666) {
        int i = idx - 65664; res[i] = cvt_in(RES, i, fl);
    } else if (idx < 66818) {
        int i = idx - 65666; c1[i] = cvt_in(C1, i, fl);
    } else if (idx < 67970) {
        int i = idx - 66818; c2[i] = cvt_in(C2, i, fl);
    }
}

// ---------------------------------------------------------------------------
// K0b: canonicalize X -> bf16 (fp32 mode only; no-op in bf16 mode).
// ---------------------------------------------------------------------------
__global__ __launch_bounds__(256) void k_xc(const void* X, u16* Xc, const int* flag)
{
    if (!flag[0]) return;
    const float* xf = (const float*)X;
    size_t i0 = ((size_t)blockIdx.x * 256 + threadIdx.x) * 8;
    float4 a = *(const float4*)&xf[i0];
    float4 b = *(const float4*)&xf[i0 + 4];
    u16 o[8] = { f2b(a.x), f2b(a.y), f2b(a.z), f2b(a.w),
                 f2b(b.x), f2b(b.y), f2b(b.z), f2b(b.w) };
    *(uint4*)&Xc[i0] = *(const uint4*)o;
}

// ---------------------------------------------------------------------------
// K1: fused QKV projection + Gram partials (fp32) + sumsq.
// ---------------------------------------------------------------------------
__global__ __launch_bounds__(256, 2) void k_qkvg(
    const void* __restrict__ X, const u16* __restrict__ Xc,
    const u16* __restrict__ W3, u16* __restrict__ vt,
    float* __restrict__ gpart, float* __restrict__ sq, float* __restrict__ sk,
    const int* __restrict__ flag)
{
    __shared__ u16 sQ[128 * 136];   // qT [cout][t]
    __shared__ u16 sT[128 * 136];   // kT then vT [cout][t]
    const u16* Xs = flag[0] ? Xc : (const u16*)X;
    const int tid = threadIdx.x, bid = blockIdx.x;
    const int b = bid >> 8, slot = bid & 255;
    const int w = tid >> 6, l = tid & 63;
    const int lr = l & 15, lq = l >> 4;
    const int tb = (w >> 1) * 64, cb = (w & 1) * 64;
    const int lr2 = l & 31, lh = l >> 5;
    const int gh = w >> 1, gd0 = (w & 1) * 32;

    f32x16 accG0, accG1;
    #pragma unroll
    for (int i = 0; i < 16; ++i) { accG0[i] = 0.f; accG1[i] = 0.f; }
    float ssq[4], ssk[4];
    #pragma unroll
    for (int i = 0; i < 4; ++i) { ssq[i] = 0.f; ssk[i] = 0.f; }

    for (int it = 0; it < 2; ++it) {
        const int n0 = (slot * 2 + it) * 128;
        const size_t xrow = (size_t)b * NTOK + n0;
        f32x4 acc[4][4];

        // ---- q GEMM ----
        #pragma unroll
        for (int mi = 0; mi < 4; ++mi)
            #pragma unroll
            for (int ni = 0; ni < 4; ++ni)
                #pragma unroll
                for (int r = 0; r < 4; ++r) acc[mi][ni][r] = 0.f;
        #pragma unroll
        for (int kk = 0; kk < 4; ++kk) {
            bf16x8 af[4], bf[4];
            #pragma unroll
            for (int mi = 0; mi < 4; ++mi)
                af[mi] = *(const bf16x8*)&Xs[(xrow + tb + mi * 16 + lr) * NCH + kk * 32 + lq * 8];
            #pragma unroll
            for (int ni = 0; ni < 4; ++ni)
                bf[ni] = *(const bf16x8*)&W3[(cb + ni * 16 + lr) * 128 + kk * 32 + lq * 8];
            #pragma unroll
            for (int mi = 0; mi < 4; ++mi)
                #pragma unroll
                for (int ni = 0; ni < 4; ++ni)
                    acc[mi][ni] = __builtin_amdgcn_mfma_f32_16x16x32_bf16(af[mi], bf[ni], acc[mi][ni], 0, 0, 0);
        }
        __syncthreads();   // prev-iter LDS reads done
        #pragma unroll
        for (int mi = 0; mi < 4; ++mi)
            #pragma unroll
            for (int ni = 0; ni < 4; ++ni)
                #pragma unroll
                for (int r = 0; r < 4; ++r) {
                    float v = acc[mi][ni][r];
                    sQ[(cb + ni * 16 + lr) * 136 + tb + mi * 16 + lq * 4 + r] = f2b(v);
                    ssq[ni] += v * v;
                }

        // ---- k GEMM ----
        #pragma unroll
        for (int mi = 0; mi < 4; ++mi)
            #pragma unroll
            for (int ni = 0; ni < 4; ++ni)
                #pragma unroll
                for (int r = 0; r < 4; ++r) acc[mi][ni][r] = 0.f;
        #pragma unroll
        for (int kk = 0; kk < 4; ++kk) {
            bf16x8 af[4], bf[4];
            #pragma unroll
            for (int mi = 0; mi < 4; ++mi)
                af[mi] = *(const bf16x8*)&Xs[(xrow + tb + mi * 16 + lr) * NCH + kk * 32 + lq * 8];
            #pragma unroll
            for (int ni = 0; ni < 4; ++ni)
                bf[ni] = *(const bf16x8*)&W3[16384 + (cb + ni * 16 + lr) * 128 + kk * 32 + lq * 8];
            #pragma unroll
            for (int mi = 0; mi < 4; ++mi)
                #pragma unroll
                for (int ni = 0; ni < 4; ++ni)
                    acc[mi][ni] = __builtin_amdgcn_mfma_f32_16x16x32_bf16(af[mi], bf[ni], acc[mi][ni], 0, 0, 0);
        }
        #pragma unroll
        for (int mi = 0; mi < 4; ++mi)
            #pragma unroll
            for (int ni = 0; ni < 4; ++ni)
                #pragma unroll
                for (int r = 0; r < 4; ++r) {
                    float v = acc[mi][ni][r];
                    sT[(cb + ni * 16 + lr) * 136 + tb + mi * 16 + lq * 4 + r] = f2b(v);
                    ssk[ni] += v * v;
                }
        __syncthreads();   // sQ, sT ready

        // ---- Gram ----
        #pragma unroll
        for (int tk = 0; tk < 8; ++tk) {
            bf16x8 a  = *(const bf16x8*)&sT[(gh * 64 + gd0 + lr2) * 136 + tk * 16 + lh * 8];
            bf16x8 b0 = *(const bf16x8*)&sQ[(gh * 64 +       lr2) * 136 + tk * 16 + lh * 8];
            bf16x8 b1 = *(const bf16x8*)&sQ[(gh * 64 + 32 +  lr2) * 136 + tk * 16 + lh * 8];
            accG0 = __builtin_amdgcn_mfma_f32_32x32x16_bf16(a, b0, accG0, 0, 0, 0);
            accG1 = __builtin_amdgcn_mfma_f32_32x32x16_bf16(a, b1, accG1, 0, 0, 0);
        }

        // ---- v GEMM (global only; overlaps Gram) ----
        #pragma unroll
        for (int mi = 0; mi < 4; ++mi)
            #pragma unroll
            for (int ni = 0; ni < 4; ++ni)
                #pragma unroll
                for (int r = 0; r < 4; ++r) acc[mi][ni][r] = 0.f;
        #pragma unroll
        for (int kk = 0; kk < 4; ++kk) {
            bf16x8 af[4], bf[4];
            #pragma unroll
            for (int mi = 0; mi < 4; ++mi)
                af[mi] = *(const bf16x8*)&Xs[(xrow + tb + mi * 16 + lr) * NCH + kk * 32 + lq * 8];
            #pragma unroll
            for (int ni = 0; ni < 4; ++ni)
                bf[ni] = *(const bf16x8*)&W3[32768 + (cb + ni * 16 + lr) * 128 + kk * 32 + lq * 8];
            #pragma unroll
            for (int mi = 0; mi < 4; ++mi)
                #pragma unroll
                for (int ni = 0; ni < 4; ++ni)
                    acc[mi][ni] = __builtin_amdgcn_mfma_f32_16x16x32_bf16(af[mi], bf[ni], acc[mi][ni], 0, 0, 0);
        }
        __syncthreads();   // Gram LDS reads done
        #pragma unroll
        for (int mi = 0; mi < 4; ++mi)
            #pragma unroll
            for (int ni = 0; ni < 4; ++ni)
                #pragma unroll
                for (int r = 0; r < 4; ++r)
                    sT[(cb + ni * 16 + lr) * 136 + tb + mi * 16 + lq * 4 + r] = f2b(acc[mi][ni][r]);
        __syncthreads();   // vT ready
        #pragma unroll
        for (int rep = 0; rep < 8; ++rep) {
            int ch = rep * 256 + tid;
            int cout = ch >> 4, t0 = (ch & 15) * 8;
            *(uint4*)&vt[((size_t)(b * NCH + cout)) * NTOK + n0 + t0] =
                *(const uint4*)&sT[cout * 136 + t0];
        }
    }

    {   // private fp32 Gram partial slot
        float* gp = gpart + ((size_t)bid * 2 + gh) * 4096;
        #pragma unroll
        for (int r = 0; r < 16; ++r) {
            int d = gd0 + (r & 3) + 8 * (r >> 2) + 4 * lh;
            gp[d * 64 + lr2]      = accG0[r];
            gp[d * 64 + 32 + lr2] = accG1[r];
        }
    }
    #pragma unroll
    for (int ni = 0; ni < 4; ++ni) {
        float a = ssq[ni], k2 = ssk[ni];
        a  += __shfl_xor(a, 16);  a  += __shfl_xor(a, 32);
        k2 += __shfl_xor(k2, 16); k2 += __shfl_xor(k2, 32);
        if (lq == 0) {
            atomicAdd(&sq[b * 128 + cb + ni * 16 + lr], a);
            atomicAdd(&sk[b * 128 + cb + ni * 16 + lr], k2);
        }
    }
}

// ---------------------------------------------------------------------------
// K2: reduce 256 fp32 Gram partials -> G.  grid (4,16) x 256.
// ---------------------------------------------------------------------------
__global__ void k_red(const float* __restrict__ gpart, float* __restrict__ G)
{
    const int bh = blockIdx.x, b = bh >> 1, h = bh & 1;
    const int de = blockIdx.y * 256 + threadIdx.x;
    float s = 0.f;
    for (int slot = 0; slot < 256; ++slot)
        s += gpart[(((size_t)b * 256 + slot) * 2 + h) * 4096 + de];
    G[(size_t)bh * 4096 + de] = s;
}

// ---------------------------------------------------------------------------
// K3: normalize + softmax + fold into WeffT[b][cout][c'].
// ---------------------------------------------------------------------------
__global__ __launch_bounds__(256) void k_attn(
    const float* __restrict__ G, const float* __restrict__ sq,
    const float* __restrict__ sk, const u16* __restrict__ Wp,
    const u16* __restrict__ RES, u16* __restrict__ WT)
{
    __shared__ float sAttn[2 * 64 * 64];
    __shared__ float sWps[128 * 16];
    __shared__ float rq[128], rk[128];
    const int b = blockIdx.x, cs = blockIdx.y, tid = threadIdx.x;

    {
        int row = tid >> 1, j0 = (tid & 1) * 8;
        bf16x8 wv = *(const bf16x8*)&Wp[row * 128 + cs * 16 + j0];
        #pragma unroll
        for (int j = 0; j < 8; ++j) sWps[row * 16 + j0 + j] = b2f((u16)wv[j]);
    }
    if (tid < 128) {
        rq[tid] = 1.f / fmaxf(sqrtf(sq[b * 128 + tid]), 1e-12f);
        rk[tid] = 1.f / fmaxf(sqrtf(sk[b * 128 + tid]), 1e-12f);
    }
    __syncthreads();
    if (tid < 128) {
        int h = tid >> 6, d = tid & 63;
        float resc = b2f(RES[h]);
        const float* g = G + ((size_t)(b * 2 + h)) * 4096 + d * 64;
        float sck = rk[h * 64 + d] * resc;
        float* row = &sAttn[(h * 64 + d) * 64];
        float m = -1e30f;
        for (int e = 0; e < 64; ++e) {
            float L = g[e] * sck * rq[h * 64 + e];
            L = fminf(fmaxf(L, -60.f), 60.f);
            row[e] = L;
            m = fmaxf(m, L);
        }
        float s = 0.f;
        for (int e = 0; e < 64; ++e) { float ex = expf(row[e] - m); row[e] = ex; s += ex; }
        float inv = 1.f / s;
        for (int e = 0; e < 64; ++e) row[e] *= inv;
    }
    __syncthreads();
    const int cp = tid >> 1;
    const int h2 = cp >> 6, e = cp & 63;
    const int j0 = (tid & 1) * 8;
    float acc8[8];
    #pragma unroll
    for (int j = 0; j < 8; ++j) acc8[j] = 0.f;
    for (int d = 0; d < 64; ++d) {
        float a = sAttn[(h2 * 64 + d) * 64 + e];
        const float* wr = &sWps[(h2 * 64 + d) * 16 + j0];
        #pragma unroll
        for (int j = 0; j < 8; ++j) acc8[j] += a * wr[j];
    }
    u16* wt = WT + (size_t)b * 16384;
    #pragma unroll
    for (int j = 0; j < 8; ++j) wt[(cs * 16 + j0 + j) * 128 + cp] = f2b(acc8[j]);
}

// ---------------------------------------------------------------------------
// K4: out_c = (v*illu)^T @ Weff + bp.  Output dtype per flag.
// ---------------------------------------------------------------------------
__global__ __launch_bounds__(256, 2) void k_outc(
    const u16* __restrict__ vt, const void* __restrict__ ILLU,
    const u16* __restrict__ WT, const u16* __restrict__ BP,
    void* __restrict__ out, const int* __restrict__ flag)
{
    __shared__ u16 sA[128 * 136];
    __shared__ u16 sB[128 * 136];
    __shared__ float sbp[128];
    const int fl = flag[0];
    const int tid = threadIdx.x;
    const int bid = blockIdx.x;
    const int b  = bid >> 9;
    const int n0 = (bid & 511) * 128;
    const int w  = tid >> 6, l = tid & 63;
    const int lr = l & 15, lq = l >> 4;
    const int tb = (w >> 1) * 64, cb = (w & 1) * 64;

    if (tid < 128) sbp[tid] = b2f(BP[tid]);
    {
        const u16* wsrc = WT + (size_t)b * 16384;
        #pragma unroll
        for (int rep = 0; rep < 8; ++rep) {
            int ch = rep * 256 + tid;
            int cout = ch >> 4, c0 = (ch & 15) * 8;
            *(uint4*)&sB[cout * 136 + c0] = *(const uint4*)&wsrc[cout * 128 + c0];
        }
    }
    {
        const float* ilf = (const float*)ILLU;
        const u16*   ilb = (const u16*)ILLU;
        #pragma unroll
        for (int rep = 0; rep < 8; ++rep) {
            int ch = rep * 256 + tid;
            int cp = ch & 127, t0 = (ch >> 7) * 8;
            bf16x8 vv = *(const bf16x8*)&vt[((size_t)(b * NCH + cp)) * NTOK + n0 + t0];
            #pragma unroll
            for (int j = 0; j < 8; ++j) {
                size_t ii = ((size_t)b * NTOK + n0 + t0 + j) * NCH + cp;
                float il = fl ? ilf[ii] : b2f(ilb[ii]);
                sA[(t0 + j) * 136 + cp] = f2b(b2f((u16)vv[j]) * il);
            }
        }
    }
    __syncthreads();

    f32x4 acc[4][4];
    #pragma unroll
    for (int mi = 0; mi < 4; ++mi)
        #pragma unroll
        for (int ni = 0; ni < 4; ++ni)
            #pragma unroll
            for (int r = 0; r < 4; ++r) acc[mi][ni][r] = 0.f;

    #pragma unroll
    for (int kk = 0; kk < 4; ++kk) {
        int k0 = kk * 32 + lq * 8;
        bf16x8 af[4], bf[4];
        #pragma unroll
        for (int mi = 0; mi < 4; ++mi)
            af[mi] = *(const bf16x8*)&sA[(tb + mi * 16 + lr) * 136 + k0];
        #pragma unroll
        for (int ni = 0; ni < 4; ++ni)
            bf[ni] = *(const bf16x8*)&sB[(cb + ni * 16 + lr) * 136 + k0];
        #pragma unroll
        for (int mi = 0; mi < 4; ++mi)
            #pragma unroll
            for (int ni = 0; ni < 4; ++ni)
                acc[mi][ni] = __builtin_amdgcn_mfma_f32_16x16x32_bf16(af[mi], bf[ni], acc[mi][ni], 0, 0, 0);
    }

    if (fl) {   // fp32 output: direct stores (16-lane 64B segments)
        float* of = (float*)out;
        const size_t rowbase = (size_t)b * NTOK + n0;
        #pragma unroll
        for (int mi = 0; mi < 4; ++mi)
            #pragma unroll
            for (int ni = 0; ni < 4; ++ni)
                #pragma unroll
                for (int r = 0; r < 4; ++r) {
                    int row = tb + mi * 16 + lq * 4 + r;
                    int col = cb + ni * 16 + lr;
                    of[(rowbase + row) * NCH + col] = acc[mi][ni][r] + sbp[col];
                }
    } else {    // bf16 output: LDS stage + uint4 stores
        u16* ob = (u16*)out;
        __syncthreads();
        #pragma unroll
        for (int mi = 0; mi < 4; ++mi)
            #pragma unroll
            for (int ni = 0; ni < 4; ++ni)
                #pragma unroll
                for (int r = 0; r < 4; ++r) {
                    int row = tb + mi * 16 + lq * 4 + r;
                    int col = cb + ni * 16 + lr;
                    sA[row * 136 + col] = f2b(acc[mi][ni][r] + sbp[col]);
                }
        __syncthreads();
        #pragma unroll
        for (int rep = 0; rep < 8; ++rep) {
            int ch = rep * 256 + tid;
            int t = ch >> 4, c0 = (ch & 15) * 8;
            *(uint4*)&ob[((size_t)b * NTOK + n0 + t) * NCH + c0] =
                *(const uint4*)&sA[t * 136 + c0];
        }
    }
}

// ---------------------------------------------------------------------------
// K5: depthwise conv3x3 -> exact GELU -> conv3x3, RMW add (dtype per flag).
// ---------------------------------------------------------------------------
#define CPD 130
__global__ __launch_bounds__(256, 2) void k_conv(
    const u16* __restrict__ vt, const u16* __restrict__ C1,
    const u16* __restrict__ C2, void* __restrict__ out,
    const int* __restrict__ flag)
{
    __shared__ u16 sV[8 * 20 * CPD];
    __shared__ u16 sP[6 * 18 * CPD];
    const int fl = flag[0];
    const int tid = threadIdx.x;
    const int x0 = blockIdx.x * 16;
    const int y0 = blockIdx.y * 4;
    const int b  = blockIdx.z;
    const int c  = tid & 127;

    float w1r[9], w2r[9];
    #pragma unroll
    for (int i = 0; i < 9; ++i) {
        w1r[i] = b2f(C1[c * 9 + i]);
        w2r[i] = b2f(C2[c * 9 + i]);
    }
    #pragma unroll
    for (int rep = 0; rep < 4; ++rep) {
        int rid = rep * 256 + tid;
        int cc = rid >> 3, y = rid & 7;
        int gy = y0 - 2 + y;
        bool yok = (gy >= 0) && (gy < IMG);
        const u16* base = vt + ((size_t)(b * NCH + cc)) * NTOK;
        #pragma unroll
        for (int x = 0; x < 20; ++x) {
            int gx = x0 - 2 + x;
            bool ok = yok && (gx >= 0) && (gx < IMG);
            sV[(y * 20 + x) * CPD + cc] = ok ? base[(size_t)gy * IMG + gx] : (u16)0;
        }
    }
    __syncthreads();
    for (int rep = 0; rep < 54; ++rep) {
        int eid = rep * 256 + tid;
        int p = eid >> 7;
        int py = p / 18, px = p % 18;
        float s = 0.f;
        #pragma unroll
        for (int dy = 0; dy < 3; ++dy)
            #pragma unroll
            for (int dx = 0; dx < 3; ++dx)
                s += w1r[dy * 3 + dx] * b2f(sV[((py + dy) * 20 + px + dx) * CPD + c]);
        float gl = 0.5f * s * (1.f + erff(s * 0.70710678118654752f));
        int iy = y0 - 1 + py, ix = x0 - 1 + px;
        bool inb = (iy >= 0) && (iy < IMG) && (ix >= 0) && (ix < IMG);
        sP[(py * 18 + px) * CPD + c] = inb ? f2b(gl) : (u16)0;
    }
    __syncthreads();
    for (int rep = 0; rep < 32; ++rep) {
        int oid = rep * 256 + tid;
        int p = oid >> 7;
        int oy = p >> 4, ox = p & 15;
        float s = 0.f;
        #pragma unroll
        for (int dy = 0; dy < 3; ++dy)
            #pragma unroll
            for (int dx = 0; dx < 3; ++dx)
                s += w2r[dy * 3 + dx] * b2f(sP[((oy + dy) * 18 + ox + dx) * CPD + c]);
        size_t oi = ((size_t)b * NTOK + (size_t)(y0 + oy) * IMG + (x0 + ox)) * NCH + c;
        if (fl) { float* of = (float*)out; of[oi] += s; }
        else    { u16* ob = (u16*)out; ob[oi] = f2b(b2f(ob[oi]) + s); }
    }
}

// ---------------------------------------------------------------------------
extern "C" void kernel_launch(void* const* d_in, const int* in_sizes, int n_in,
                              void* d_out, int out_size, void* d_ws, size_t ws_size,
                              hipStream_t stream)
{
    const void* X   = d_in[0];
    const void* IL  = d_in[1];
    const void* Wq  = d_in[2];
    const void* Wk  = d_in[3];
    const void* Wv  = d_in[4];
    const void* RES = d_in[5];
    const void* Wp  = d_in[6];
    const void* BP  = d_in[7];
    const void* C1  = d_in[8];
    const void* C2  = d_in[9];
    char* ws = (char*)d_ws;

    u16*   vt   = (u16*)(ws + OFF_VT);
    float* sq   = (float*)(ws + OFF_SQ);
    float* sk   = (float*)(ws + OFF_SK);
    u16*   WTE  = (u16*)(ws + OFF_WTE);
    float* G    = (float*)(ws + OFF_G);
    u16*   w3   = (u16*)(ws + OFF_W3);
    u16*   wpc  = (u16*)(ws + OFF_WP);
    u16*   bpc  = (u16*)(ws + OFF_BP);
    u16*   resc = (u16*)(ws + OFF_RES);
    u16*   c1c  = (u16*)(ws + OFF_C1);
    u16*   c2c  = (u16*)(ws + OFF_C2);
    int*   flag = (int*)(ws + OFF_FLAG);
    float* gpart = (float*)d_out;             // d_out scratch (dead after k_red)
    u16*   Xc    = (u16*)d_out + XC_U16;      // fp32 mode only

    hipMemsetAsync((void*)(ws + OFF_SQ), 0, 2048, stream);
    hipLaunchKernelGGL(k_detect, dim3(1),         dim3(256), 0, stream, X, flag);
    hipLaunchKernelGGL(k_prep,   dim3(266),       dim3(256), 0, stream,
                       Wq, Wk, Wv, Wp, BP, RES, C1, C2,
                       w3, wpc, bpc, resc, c1c, c2c, flag);
    hipLaunchKernelGGL(k_xc,     dim3(8192),      dim3(256), 0, stream, X, Xc, flag);
    hipLaunchKernelGGL(k_qkvg,   dim3(512),       dim3(256), 0, stream,
                       X, Xc, w3, vt, gpart, sq, sk, flag);
    hipLaunchKernelGGL(k_red,    dim3(4, 16),     dim3(256), 0, stream, gpart, G);
    hipLaunchKernelGGL(k_attn,   dim3(2, 8),      dim3(256), 0, stream, G, sq, sk, wpc, resc, WTE);
    hipLaunchKernelGGL(k_outc,   dim3(1024),      dim3(256), 0, stream, vt, IL, WTE, bpc, d_out, flag);
    hipLaunchKernelGGL(k_conv,   dim3(16, 64, 2), dim3(256), 0, stream, vt, c1c, c2c, d_out, flag);
}

// Round 4
// 390.606 us; speedup vs baseline: 1.4851x; 1.4851x over previous
//
#include <hip/hip_runtime.h>
#include <hip/hip_bf16.h>
#include <math.h>

typedef unsigned short u16;
typedef short bf16x8 __attribute__((ext_vector_type(8)));
typedef float f32x4  __attribute__((ext_vector_type(4)));
typedef float f32x16 __attribute__((ext_vector_type(16)));

#define IMG  256
#define NTOK 65536
#define NCH  128

// ---- ws layout (bytes) ----
#define OFF_VT   0ULL           // bf16 ungated v [b][c][n], 32 MiB
#define OFF_SQ   33554432ULL    // fp32 [b][128]
#define OFF_SK   33555456ULL    // fp32 [b][128]
#define OFF_WTE  33556480ULL    // bf16 WeffT [b][cout][c'] (64 KiB)
#define OFF_G    33622016ULL    // fp32 [bh][64][64] (64 KiB)
#define OFF_W3   33687552ULL    // bf16 W^T x3 [g][cout][cin] (96 KiB)
#define OFF_WP   33785856ULL    // bf16 Wp (32 KiB)
#define OFF_BP   33818624ULL    // bf16 bp
#define OFF_RES  33818880ULL    // bf16 rescale
#define OFF_C1   33819136ULL    // bf16 conv1 w
#define OFF_C2   33821696ULL    // bf16 conv2 w
#define OFF_FLAG 33824256ULL    // int: 1 = inputs are fp32
#define OFF_P2   33824768ULL    // bf16 conv branch [b][c][n], 32 MiB (fast path)
#define WS_NEED_FAST (OFF_P2 + 33554432ULL)

// ---- d_out scratch (dead after use; k_outc overwrites d_out fully) ----
#define XC_U16    8388608ULL    // bf16 canonical X (fp32 mode only)

static __device__ __forceinline__ float b2f(u16 u) {
    union { float f; unsigned int i; } x; x.i = ((unsigned int)u) << 16; return x.f;
}
static __device__ __forceinline__ u16 f2b(float f) {
    __hip_bfloat16 h = __float2bfloat16(f);
    return *reinterpret_cast<u16*>(&h);
}
static __device__ __forceinline__ u16 cvt_in(const void* p, int i, int fl) {
    return fl ? f2b(((const float*)p)[i]) : ((const u16*)p)[i];
}

// ---------------------------------------------------------------------------
// dtype probe: fp32 N(0,1) words lie in [1e-4,1e4]; bf16-pair bit patterns don't.
// ---------------------------------------------------------------------------
__global__ void k_detect(const void* X, int* flag)
{
    __shared__ int cnt;
    if (threadIdx.x == 0) cnt = 0;
    __syncthreads();
    const float* xf = (const float*)X;
    int c = 0;
    #pragma unroll
    for (int i = 0; i < 4; ++i) {
        float v = fabsf(xf[threadIdx.x * 4 + i]);
        if (v > 1e-4f && v < 1e4f) c++;
    }
    atomicAdd(&cnt, c);
    __syncthreads();
    if (threadIdx.x == 0) flag[0] = (cnt > 512) ? 1 : 0;
}

// ---------------------------------------------------------------------------
// canonicalize small weights into ws (bf16), incl. transposed W^T x3.
// ---------------------------------------------------------------------------
__global__ void k_prep(const void* Wq, const void* Wk, const void* Wv,
                       const void* Wp, const void* BP, const void* RES,
                       const void* C1, const void* C2,
                       u16* w3, u16* wp, u16* bp, u16* res, u16* c1, u16* c2,
                       const int* flag)
{
    const int fl = flag[0];
    int idx = blockIdx.x * 256 + threadIdx.x;
    if (idx < 49152) {
        int g = idx >> 14, r = idx & 16383;
        int cin = r >> 7, cout = r & 127;
        const void* s = (g == 0) ? Wq : (g == 1) ? Wk : Wv;
        w3[g * 16384 + cout * 128 + cin] = cvt_in(s, cin * 128 + cout, fl);
    } else if (idx < 65536) {
        int i = idx - 49152; wp[i] = cvt_in(Wp, i, fl);
    } else if (idx < 65664) {
        int i = idx - 65536; bp[i] = cvt_in(BP, i, fl);
    } else if (idx < 65666) {
        int i = idx - 65664; res[i] = cvt_in(RES, i, fl);
    } else if (idx < 66818) {
        int i = idx - 65666; c1[i] = cvt_in(C1, i, fl);
    } else if (idx < 67970) {
        int i = idx - 66818; c2[i] = cvt_in(C2, i, fl);
    }
}

// ---------------------------------------------------------------------------
// canonicalize X -> bf16 (fp32 mode only).
// ---------------------------------------------------------------------------
__global__ __launch_bounds__(256) void k_xc(const void* X, u16* Xc, const int* flag)
{
    if (!flag[0]) return;
    const float* xf = (const float*)X;
    size_t i0 = ((size_t)blockIdx.x * 256 + threadIdx.x) * 8;
    float4 a = *(const float4*)&xf[i0];
    float4 b = *(const float4*)&xf[i0 + 4];
    u16 o[8] = { f2b(a.x), f2b(a.y), f2b(a.z), f2b(a.w),
                 f2b(b.x), f2b(b.y), f2b(b.z), f2b(b.w) };
    *(uint4*)&Xc[i0] = *(const uint4*)o;
}

// ---------------------------------------------------------------------------
// K1: fused QKV projection + Gram partials (fp32) + sumsq.
// A-fragments (X tile) loaded ONCE into registers, reused for q/k/v.
// ---------------------------------------------------------------------------
__global__ __launch_bounds__(256, 2) void k_qkvg(
    const void* __restrict__ X, const u16* __restrict__ Xc,
    const u16* __restrict__ W3, u16* __restrict__ vt,
    float* __restrict__ gpart, float* __restrict__ sq, float* __restrict__ sk,
    const int* __restrict__ flag)
{
    __shared__ u16 sQ[128 * 136];   // qT [cout][t]
    __shared__ u16 sT[128 * 136];   // kT then vT [cout][t]
    const u16* Xs = flag[0] ? Xc : (const u16*)X;
    const int tid = threadIdx.x, bid = blockIdx.x;
    const int b = bid >> 8, slot = bid & 255;
    const int w = tid >> 6, l = tid & 63;
    const int lr = l & 15, lq = l >> 4;
    const int tb = (w >> 1) * 64, cb = (w & 1) * 64;
    const int lr2 = l & 31, lh = l >> 5;
    const int gh = w >> 1, gd0 = (w & 1) * 32;

    f32x16 accG0, accG1;
    #pragma unroll
    for (int i = 0; i < 16; ++i) { accG0[i] = 0.f; accG1[i] = 0.f; }
    float ssq[4], ssk[4];
    #pragma unroll
    for (int i = 0; i < 4; ++i) { ssq[i] = 0.f; ssk[i] = 0.f; }

    for (int it = 0; it < 2; ++it) {
        const int n0 = (slot * 2 + it) * 128;
        const size_t xrow = (size_t)b * NTOK + n0;
        f32x4 acc[4][4];

        // ---- load A fragments once (shared across q/k/v) ----
        bf16x8 af[4][4];   // [kk][mi]
        #pragma unroll
        for (int kk = 0; kk < 4; ++kk)
            #pragma unroll
            for (int mi = 0; mi < 4; ++mi)
                af[kk][mi] = *(const bf16x8*)&Xs[(xrow + tb + mi * 16 + lr) * NCH + kk * 32 + lq * 8];

        // ---- q GEMM ----
        #pragma unroll
        for (int mi = 0; mi < 4; ++mi)
            #pragma unroll
            for (int ni = 0; ni < 4; ++ni)
                #pragma unroll
                for (int r = 0; r < 4; ++r) acc[mi][ni][r] = 0.f;
        #pragma unroll
        for (int kk = 0; kk < 4; ++kk) {
            bf16x8 bf[4];
            #pragma unroll
            for (int ni = 0; ni < 4; ++ni)
                bf[ni] = *(const bf16x8*)&W3[(cb + ni * 16 + lr) * 128 + kk * 32 + lq * 8];
            #pragma unroll
            for (int mi = 0; mi < 4; ++mi)
                #pragma unroll
                for (int ni = 0; ni < 4; ++ni)
                    acc[mi][ni] = __builtin_amdgcn_mfma_f32_16x16x32_bf16(af[kk][mi], bf[ni], acc[mi][ni], 0, 0, 0);
        }
        __syncthreads();   // prev-iter LDS reads done
        #pragma unroll
        for (int mi = 0; mi < 4; ++mi)
            #pragma unroll
            for (int ni = 0; ni < 4; ++ni)
                #pragma unroll
                for (int r = 0; r < 4; ++r) {
                    float v = acc[mi][ni][r];
                    sQ[(cb + ni * 16 + lr) * 136 + tb + mi * 16 + lq * 4 + r] = f2b(v);
                    ssq[ni] += v * v;
                }

        // ---- k GEMM ----
        #pragma unroll
        for (int mi = 0; mi < 4; ++mi)
            #pragma unroll
            for (int ni = 0; ni < 4; ++ni)
                #pragma unroll
                for (int r = 0; r < 4; ++r) acc[mi][ni][r] = 0.f;
        #pragma unroll
        for (int kk = 0; kk < 4; ++kk) {
            bf16x8 bf[4];
            #pragma unroll
            for (int ni = 0; ni < 4; ++ni)
                bf[ni] = *(const bf16x8*)&W3[16384 + (cb + ni * 16 + lr) * 128 + kk * 32 + lq * 8];
            #pragma unroll
            for (int mi = 0; mi < 4; ++mi)
                #pragma unroll
                for (int ni = 0; ni < 4; ++ni)
                    acc[mi][ni] = __builtin_amdgcn_mfma_f32_16x16x32_bf16(af[kk][mi], bf[ni], acc[mi][ni], 0, 0, 0);
        }
        #pragma unroll
        for (int mi = 0; mi < 4; ++mi)
            #pragma unroll
            for (int ni = 0; ni < 4; ++ni)
                #pragma unroll
                for (int r = 0; r < 4; ++r) {
                    float v = acc[mi][ni][r];
                    sT[(cb + ni * 16 + lr) * 136 + tb + mi * 16 + lq * 4 + r] = f2b(v);
                    ssk[ni] += v * v;
                }
        __syncthreads();   // sQ, sT ready

        // ---- Gram ----
        #pragma unroll
        for (int tk = 0; tk < 8; ++tk) {
            bf16x8 a  = *(const bf16x8*)&sT[(gh * 64 + gd0 + lr2) * 136 + tk * 16 + lh * 8];
            bf16x8 b0 = *(const bf16x8*)&sQ[(gh * 64 +       lr2) * 136 + tk * 16 + lh * 8];
            bf16x8 b1 = *(const bf16x8*)&sQ[(gh * 64 + 32 +  lr2) * 136 + tk * 16 + lh * 8];
            accG0 = __builtin_amdgcn_mfma_f32_32x32x16_bf16(a, b0, accG0, 0, 0, 0);
            accG1 = __builtin_amdgcn_mfma_f32_32x32x16_bf16(a, b1, accG1, 0, 0, 0);
        }

        // ---- v GEMM ----
        #pragma unroll
        for (int mi = 0; mi < 4; ++mi)
            #pragma unroll
            for (int ni = 0; ni < 4; ++ni)
                #pragma unroll
                for (int r = 0; r < 4; ++r) acc[mi][ni][r] = 0.f;
        #pragma unroll
        for (int kk = 0; kk < 4; ++kk) {
            bf16x8 bf[4];
            #pragma unroll
            for (int ni = 0; ni < 4; ++ni)
                bf[ni] = *(const bf16x8*)&W3[32768 + (cb + ni * 16 + lr) * 128 + kk * 32 + lq * 8];
            #pragma unroll
            for (int mi = 0; mi < 4; ++mi)
                #pragma unroll
                for (int ni = 0; ni < 4; ++ni)
                    acc[mi][ni] = __builtin_amdgcn_mfma_f32_16x16x32_bf16(af[kk][mi], bf[ni], acc[mi][ni], 0, 0, 0);
        }
        __syncthreads();   // Gram LDS reads done
        #pragma unroll
        for (int mi = 0; mi < 4; ++mi)
            #pragma unroll
            for (int ni = 0; ni < 4; ++ni)
                #pragma unroll
                for (int r = 0; r < 4; ++r)
                    sT[(cb + ni * 16 + lr) * 136 + tb + mi * 16 + lq * 4 + r] = f2b(acc[mi][ni][r]);
        __syncthreads();   // vT ready
        #pragma unroll
        for (int rep = 0; rep < 8; ++rep) {
            int ch = rep * 256 + tid;
            int cout = ch >> 4, t0 = (ch & 15) * 8;
            *(uint4*)&vt[((size_t)(b * NCH + cout)) * NTOK + n0 + t0] =
                *(const uint4*)&sT[cout * 136 + t0];
        }
    }

    {   // private fp32 Gram partial slot
        float* gp = gpart + ((size_t)bid * 2 + gh) * 4096;
        #pragma unroll
        for (int r = 0; r < 16; ++r) {
            int d = gd0 + (r & 3) + 8 * (r >> 2) + 4 * lh;
            gp[d * 64 + lr2]      = accG0[r];
            gp[d * 64 + 32 + lr2] = accG1[r];
        }
    }
    #pragma unroll
    for (int ni = 0; ni < 4; ++ni) {
        float a = ssq[ni], k2 = ssk[ni];
        a  += __shfl_xor(a, 16);  a  += __shfl_xor(a, 32);
        k2 += __shfl_xor(k2, 16); k2 += __shfl_xor(k2, 32);
        if (lq == 0) {
            atomicAdd(&sq[b * 128 + cb + ni * 16 + lr], a);
            atomicAdd(&sk[b * 128 + cb + ni * 16 + lr], k2);
        }
    }
}

// ---------------------------------------------------------------------------
// K2: reduce 256 fp32 Gram partials -> G.
// ---------------------------------------------------------------------------
__global__ void k_red(const float* __restrict__ gpart, float* __restrict__ G)
{
    const int bh = blockIdx.x, b = bh >> 1, h = bh & 1;
    const int de = blockIdx.y * 256 + threadIdx.x;
    float s = 0.f;
    for (int slot = 0; slot < 256; ++slot)
        s += gpart[(((size_t)b * 256 + slot) * 2 + h) * 4096 + de];
    G[(size_t)bh * 4096 + de] = s;
}

// ---------------------------------------------------------------------------
// K3: normalize + softmax + fold into WeffT[b][cout][c'].
// ---------------------------------------------------------------------------
__global__ __launch_bounds__(256) void k_attn(
    const float* __restrict__ G, const float* __restrict__ sq,
    const float* __restrict__ sk, const u16* __restrict__ Wp,
    const u16* __restrict__ RES, u16* __restrict__ WT)
{
    __shared__ float sAttn[2 * 64 * 64];
    __shared__ float sWps[128 * 16];
    __shared__ float rq[128], rk[128];
    const int b = blockIdx.x, cs = blockIdx.y, tid = threadIdx.x;

    {
        int row = tid >> 1, j0 = (tid & 1) * 8;
        bf16x8 wv = *(const bf16x8*)&Wp[row * 128 + cs * 16 + j0];
        #pragma unroll
        for (int j = 0; j < 8; ++j) sWps[row * 16 + j0 + j] = b2f((u16)wv[j]);
    }
    if (tid < 128) {
        rq[tid] = 1.f / fmaxf(sqrtf(sq[b * 128 + tid]), 1e-12f);
        rk[tid] = 1.f / fmaxf(sqrtf(sk[b * 128 + tid]), 1e-12f);
    }
    __syncthreads();
    if (tid < 128) {
        int h = tid >> 6, d = tid & 63;
        float resc = b2f(RES[h]);
        const float* g = G + ((size_t)(b * 2 + h)) * 4096 + d * 64;
        float sck = rk[h * 64 + d] * resc;
        float* row = &sAttn[(h * 64 + d) * 64];
        float m = -1e30f;
        for (int e = 0; e < 64; ++e) {
            float L = g[e] * sck * rq[h * 64 + e];
            L = fminf(fmaxf(L, -60.f), 60.f);
            row[e] = L;
            m = fmaxf(m, L);
        }
        float s = 0.f;
        for (int e = 0; e < 64; ++e) { float ex = expf(row[e] - m); row[e] = ex; s += ex; }
        float inv = 1.f / s;
        for (int e = 0; e < 64; ++e) row[e] *= inv;
    }
    __syncthreads();
    const int cp = tid >> 1;
    const int h2 = cp >> 6, e = cp & 63;
    const int j0 = (tid & 1) * 8;
    float acc8[8];
    #pragma unroll
    for (int j = 0; j < 8; ++j) acc8[j] = 0.f;
    for (int d = 0; d < 64; ++d) {
        float a = sAttn[(h2 * 64 + d) * 64 + e];
        const float* wr = &sWps[(h2 * 64 + d) * 16 + j0];
        #pragma unroll
        for (int j = 0; j < 8; ++j) acc8[j] += a * wr[j];
    }
    u16* wt = WT + (size_t)b * 16384;
    #pragma unroll
    for (int j = 0; j < 8; ++j) wt[(cs * 16 + j0 + j) * 128 + cp] = f2b(acc8[j]);
}

// ---------------------------------------------------------------------------
// K-conv (fast): channel-plane strips. Block = (strip of 32 rows, c, b).
// Coalesced row loads; thread-per-column sliding window; writes p2 [b][c][n].
// ---------------------------------------------------------------------------
__global__ __launch_bounds__(256, 4) void k_conv2p(
    const u16* __restrict__ vt, const u16* __restrict__ C1,
    const u16* __restrict__ C2, u16* __restrict__ p2)
{
    __shared__ u16 sV[36 * 256];   // v rows y0-2 .. y0+33 (zero-padded off-image)
    __shared__ u16 sP[34 * 256];   // gelu(conv1) rows y0-1 .. y0+32 (zeroed off-image)
    const int tid = threadIdx.x;
    const int y0 = blockIdx.x * 32;
    const int c  = blockIdx.y;
    const int b  = blockIdx.z;
    const u16* plane = vt + ((size_t)(b * NCH + c)) * NTOK;

    float w1[9], w2[9];
    #pragma unroll
    for (int i = 0; i < 9; ++i) { w1[i] = b2f(C1[c * 9 + i]); w2[i] = b2f(C2[c * 9 + i]); }

    // load 36 rows x 256 cols as uint4 (1152 chunks)
    #pragma unroll
    for (int rep = 0; rep < 5; ++rep) {
        int idx = rep * 256 + tid;
        if (idx < 1152) {
            int row = idx >> 5, xq = (idx & 31) * 8;
            int gy = y0 - 2 + row;
            uint4 vzero = make_uint4(0, 0, 0, 0);
            uint4 v = (gy >= 0 && gy < IMG) ? *(const uint4*)&plane[(size_t)gy * IMG + xq] : vzero;
            *(uint4*)&sV[row * 256 + xq] = v;
        }
    }
    __syncthreads();

    const int x = tid;
    // conv1 + exact gelu, sliding 3x3 window down the column
    {
        float l0, m0, r0, l1, m1, r1;
        m0 = b2f(sV[x]);
        l0 = (x > 0)   ? b2f(sV[x - 1]) : 0.f;
        r0 = (x < 255) ? b2f(sV[x + 1]) : 0.f;
        m1 = b2f(sV[256 + x]);
        l1 = (x > 0)   ? b2f(sV[256 + x - 1]) : 0.f;
        r1 = (x < 255) ? b2f(sV[256 + x + 1]) : 0.f;
        for (int j = 0; j < 34; ++j) {
            int base = (j + 2) * 256 + x;
            float m2 = b2f(sV[base]);
            float l2 = (x > 0)   ? b2f(sV[base - 1]) : 0.f;
            float r2 = (x < 255) ? b2f(sV[base + 1]) : 0.f;
            float s = w1[0] * l0 + w1[1] * m0 + w1[2] * r0
                    + w1[3] * l1 + w1[4] * m1 + w1[5] * r1
                    + w1[6] * l2 + w1[7] * m2 + w1[8] * r2;
            int iy = y0 - 1 + j;
            float gl = 0.5f * s * (1.f + erff(s * 0.70710678118654752f));
            sP[j * 256 + x] = (iy >= 0 && iy < IMG) ? f2b(gl) : (u16)0;
            l0 = l1; m0 = m1; r0 = r1;
            l1 = l2; m1 = m2; r1 = r2;
        }
    }
    __syncthreads();

    // conv2, write p2 channel-planar
    {
        u16* dst = p2 + ((size_t)(b * NCH + c)) * NTOK;
        float l0, m0, r0, l1, m1, r1;
        m0 = b2f(sP[x]);
        l0 = (x > 0)   ? b2f(sP[x - 1]) : 0.f;
        r0 = (x < 255) ? b2f(sP[x + 1]) : 0.f;
        m1 = b2f(sP[256 + x]);
        l1 = (x > 0)   ? b2f(sP[256 + x - 1]) : 0.f;
        r1 = (x < 255) ? b2f(sP[256 + x + 1]) : 0.f;
        for (int i = 0; i < 32; ++i) {
            int base = (i + 2) * 256 + x;
            float m2 = b2f(sP[base]);
            float l2 = (x > 0)   ? b2f(sP[base - 1]) : 0.f;
            float r2 = (x < 255) ? b2f(sP[base + 1]) : 0.f;
            float s = w2[0] * l0 + w2[1] * m0 + w2[2] * r0
                    + w2[3] * l1 + w2[4] * m1 + w2[5] * r1
                    + w2[6] * l2 + w2[7] * m2 + w2[8] * r2;
            dst[(size_t)(y0 + i) * IMG + x] = f2b(s);
            l0 = l1; m0 = m1; r0 = r1;
            l1 = l2; m1 = m2; r1 = r2;
        }
    }
}

// ---------------------------------------------------------------------------
// K4: out = (v*illu)^T @ Weff + bp (+ p2 if fast path). dtype per flag.
// ---------------------------------------------------------------------------
__global__ __launch_bounds__(256, 2) void k_outc(
    const u16* __restrict__ vt, const void* __restrict__ ILLU,
    const u16* __restrict__ WT, const u16* __restrict__ BP,
    const u16* __restrict__ p2, void* __restrict__ out,
    const int* __restrict__ flag, int use_p2)
{
    __shared__ u16 sA[128 * 136];
    __shared__ u16 sB[128 * 136];
    __shared__ float sbp[128];
    const int fl = flag[0];
    const int tid = threadIdx.x;
    const int bid = blockIdx.x;
    const int b  = bid >> 9;
    const int n0 = (bid & 511) * 128;
    const int w  = tid >> 6, l = tid & 63;
    const int lr = l & 15, lq = l >> 4;
    const int tb = (w >> 1) * 64, cb = (w & 1) * 64;

    if (tid < 128) sbp[tid] = b2f(BP[tid]);
    {
        const u16* wsrc = WT + (size_t)b * 16384;
        #pragma unroll
        for (int rep = 0; rep < 8; ++rep) {
            int ch = rep * 256 + tid;
            int cout = ch >> 4, c0 = (ch & 15) * 8;
            *(uint4*)&sB[cout * 136 + c0] = *(const uint4*)&wsrc[cout * 128 + c0];
        }
    }
    {
        const float* ilf = (const float*)ILLU;
        const u16*   ilb = (const u16*)ILLU;
        #pragma unroll
        for (int rep = 0; rep < 8; ++rep) {
            int ch = rep * 256 + tid;
            int cp = ch & 127, t0 = (ch >> 7) * 8;
            bf16x8 vv = *(const bf16x8*)&vt[((size_t)(b * NCH + cp)) * NTOK + n0 + t0];
            #pragma unroll
            for (int j = 0; j < 8; ++j) {
                size_t ii = ((size_t)b * NTOK + n0 + t0 + j) * NCH + cp;
                float il = fl ? ilf[ii] : b2f(ilb[ii]);
                sA[(t0 + j) * 136 + cp] = f2b(b2f((u16)vv[j]) * il);
            }
        }
    }
    __syncthreads();

    f32x4 acc[4][4];
    #pragma unroll
    for (int mi = 0; mi < 4; ++mi)
        #pragma unroll
        for (int ni = 0; ni < 4; ++ni)
            #pragma unroll
            for (int r = 0; r < 4; ++r) acc[mi][ni][r] = 0.f;

    #pragma unroll
    for (int kk = 0; kk < 4; ++kk) {
        int k0 = kk * 32 + lq * 8;
        bf16x8 af[4], bf[4];
        #pragma unroll
        for (int mi = 0; mi < 4; ++mi)
            af[mi] = *(const bf16x8*)&sA[(tb + mi * 16 + lr) * 136 + k0];
        #pragma unroll
        for (int ni = 0; ni < 4; ++ni)
            bf[ni] = *(const bf16x8*)&sB[(cb + ni * 16 + lr) * 136 + k0];
        #pragma unroll
        for (int mi = 0; mi < 4; ++mi)
            #pragma unroll
            for (int ni = 0; ni < 4; ++ni)
                acc[mi][ni] = __builtin_amdgcn_mfma_f32_16x16x32_bf16(af[mi], bf[ni], acc[mi][ni], 0, 0, 0);
    }

    if (use_p2) {   // stage conv branch tile into sB (transpose to [t][c])
        __syncthreads();
        #pragma unroll
        for (int rep = 0; rep < 8; ++rep) {
            int ch = rep * 256 + tid;
            int cp = ch & 127, t0 = (ch >> 7) * 8;
            bf16x8 pv = *(const bf16x8*)&p2[((size_t)(b * NCH + cp)) * NTOK + n0 + t0];
            #pragma unroll
            for (int j = 0; j < 8; ++j) sB[(t0 + j) * 136 + cp] = (u16)pv[j];
        }
        __syncthreads();
        #pragma unroll
        for (int mi = 0; mi < 4; ++mi)
            #pragma unroll
            for (int ni = 0; ni < 4; ++ni)
                #pragma unroll
                for (int r = 0; r < 4; ++r) {
                    int row = tb + mi * 16 + lq * 4 + r;
                    int col = cb + ni * 16 + lr;
                    acc[mi][ni][r] += b2f(sB[row * 136 + col]);
                }
    }

    if (fl) {   // fp32 output: direct stores
        float* of = (float*)out;
        const size_t rowbase = (size_t)b * NTOK + n0;
        #pragma unroll
        for (int mi = 0; mi < 4; ++mi)
            #pragma unroll
            for (int ni = 0; ni < 4; ++ni)
                #pragma unroll
                for (int r = 0; r < 4; ++r) {
                    int row = tb + mi * 16 + lq * 4 + r;
                    int col = cb + ni * 16 + lr;
                    of[(rowbase + row) * NCH + col] = acc[mi][ni][r] + sbp[col];
                }
    } else {    // bf16 output: LDS stage + uint4 stores
        u16* ob = (u16*)out;
        __syncthreads();
        #pragma unroll
        for (int mi = 0; mi < 4; ++mi)
            #pragma unroll
            for (int ni = 0; ni < 4; ++ni)
                #pragma unroll
                for (int r = 0; r < 4; ++r) {
                    int row = tb + mi * 16 + lq * 4 + r;
                    int col = cb + ni * 16 + lr;
                    sA[row * 136 + col] = f2b(acc[mi][ni][r] + sbp[col]);
                }
        __syncthreads();
        #pragma unroll
        for (int rep = 0; rep < 8; ++rep) {
            int ch = rep * 256 + tid;
            int t = ch >> 4, c0 = (ch & 15) * 8;
            *(uint4*)&ob[((size_t)b * NTOK + n0 + t) * NCH + c0] =
                *(const uint4*)&sA[t * 136 + c0];
        }
    }
}

// ---------------------------------------------------------------------------
// Legacy conv (fallback when ws too small): RMW into out.
// ---------------------------------------------------------------------------
#define CPD 130
__global__ __launch_bounds__(256, 2) void k_conv_rmw(
    const u16* __restrict__ vt, const u16* __restrict__ C1,
    const u16* __restrict__ C2, void* __restrict__ out,
    const int* __restrict__ flag)
{
    __shared__ u16 sV[8 * 20 * CPD];
    __shared__ u16 sP[6 * 18 * CPD];
    const int fl = flag[0];
    const int tid = threadIdx.x;
    const int x0 = blockIdx.x * 16;
    const int y0 = blockIdx.y * 4;
    const int b  = blockIdx.z;
    const int c  = tid & 127;

    float w1r[9], w2r[9];
    #pragma unroll
    for (int i = 0; i < 9; ++i) {
        w1r[i] = b2f(C1[c * 9 + i]);
        w2r[i] = b2f(C2[c * 9 + i]);
    }
    #pragma unroll
    for (int rep = 0; rep < 4; ++rep) {
        int rid = rep * 256 + tid;
        int cc = rid >> 3, y = rid & 7;
        int gy = y0 - 2 + y;
        bool yok = (gy >= 0) && (gy < IMG);
        const u16* base = vt + ((size_t)(b * NCH + cc)) * NTOK;
        #pragma unroll
        for (int xx = 0; xx < 20; ++xx) {
            int gx = x0 - 2 + xx;
            bool ok = yok && (gx >= 0) && (gx < IMG);
            sV[(y * 20 + xx) * CPD + cc] = ok ? base[(size_t)gy * IMG + gx] : (u16)0;
        }
    }
    __syncthreads();
    for (int rep = 0; rep < 54; ++rep) {
        int eid = rep * 256 + tid;
        int p = eid >> 7;
        int py = p / 18, px = p % 18;
        float s = 0.f;
        #pragma unroll
        for (int dy = 0; dy < 3; ++dy)
            #pragma unroll
            for (int dx = 0; dx < 3; ++dx)
                s += w1r[dy * 3 + dx] * b2f(sV[((py + dy) * 20 + px + dx) * CPD + c]);
        float gl = 0.5f * s * (1.f + erff(s * 0.70710678118654752f));
        int iy = y0 - 1 + py, ix = x0 - 1 + px;
        bool inb = (iy >= 0) && (iy < IMG) && (ix >= 0) && (ix < IMG);
        sP[(py * 18 + px) * CPD + c] = inb ? f2b(gl) : (u16)0;
    }
    __syncthreads();
    for (int rep = 0; rep < 32; ++rep) {
        int oid = rep * 256 + tid;
        int p = oid >> 7;
        int oy = p >> 4, ox = p & 15;
        float s = 0.f;
        #pragma unroll
        for (int dy = 0; dy < 3; ++dy)
            #pragma unroll
            for (int dx = 0; dx < 3; ++dx)
                s += w2r[dy * 3 + dx] * b2f(sP[((oy + dy) * 18 + ox + dx) * CPD + c]);
        size_t oi = ((size_t)b * NTOK + (size_t)(y0 + oy) * IMG + (x0 + ox)) * NCH + c;
        if (fl) { float* of = (float*)out; of[oi] += s; }
        else    { u16* ob = (u16*)out; ob[oi] = f2b(b2f(ob[oi]) + s); }
    }
}

// ---------------------------------------------------------------------------
extern "C" void kernel_launch(void* const* d_in, const int* in_sizes, int n_in,
                              void* d_out, int out_size, void* d_ws, size_t ws_size,
                              hipStream_t stream)
{
    const void* X   = d_in[0];
    const void* IL  = d_in[1];
    const void* Wq  = d_in[2];
    const void* Wk  = d_in[3];
    const void* Wv  = d_in[4];
    const void* RES = d_in[5];
    const void* Wp  = d_in[6];
    const void* BP  = d_in[7];
    const void* C1  = d_in[8];
    const void* C2  = d_in[9];
    char* ws = (char*)d_ws;

    u16*   vt   = (u16*)(ws + OFF_VT);
    float* sq   = (float*)(ws + OFF_SQ);
    float* sk   = (float*)(ws + OFF_SK);
    u16*   WTE  = (u16*)(ws + OFF_WTE);
    float* G    = (float*)(ws + OFF_G);
    u16*   w3   = (u16*)(ws + OFF_W3);
    u16*   wpc  = (u16*)(ws + OFF_WP);
    u16*   bpc  = (u16*)(ws + OFF_BP);
    u16*   resc = (u16*)(ws + OFF_RES);
    u16*   c1c  = (u16*)(ws + OFF_C1);
    u16*   c2c  = (u16*)(ws + OFF_C2);
    int*   flag = (int*)(ws + OFF_FLAG);
    u16*   p2   = (u16*)(ws + OFF_P2);
    float* gpart = (float*)d_out;
    u16*   Xc    = (u16*)d_out + XC_U16;

    const bool fast = (ws_size >= WS_NEED_FAST);

    hipMemsetAsync((void*)(ws + OFF_SQ), 0, 2048, stream);
    hipLaunchKernelGGL(k_detect, dim3(1),         dim3(256), 0, stream, X, flag);
    hipLaunchKernelGGL(k_prep,   dim3(266),       dim3(256), 0, stream,
                       Wq, Wk, Wv, Wp, BP, RES, C1, C2,
                       w3, wpc, bpc, resc, c1c, c2c, flag);
    hipLaunchKernelGGL(k_xc,     dim3(8192),      dim3(256), 0, stream, X, Xc, flag);
    hipLaunchKernelGGL(k_qkvg,   dim3(512),       dim3(256), 0, stream,
                       X, Xc, w3, vt, gpart, sq, sk, flag);
    if (fast)
        hipLaunchKernelGGL(k_conv2p, dim3(8, 128, 2), dim3(256), 0, stream, vt, c1c, c2c, p2);
    hipLaunchKernelGGL(k_red,    dim3(4, 16),     dim3(256), 0, stream, gpart, G);
    hipLaunchKernelGGL(k_attn,   dim3(2, 8),      dim3(256), 0, stream, G, sq, sk, wpc, resc, WTE);
    hipLaunchKernelGGL(k_outc,   dim3(1024),      dim3(256), 0, stream,
                       vt, IL, WTE, bpc, p2, d_out, flag, fast ? 1 : 0);
    if (!fast)
        hipLaunchKernelGGL(k_conv_rmw, dim3(16, 64, 2), dim3(256), 0, stream,
                           vt, c1c, c2c, d_out, flag);
}